// Round 9
// baseline (586.417 us; speedup 1.0000x reference)
//
#include <hip/hip_runtime.h>
#include <stdint.h>
#include <math.h>

#define N_NODES  10000
#define N_EDGES  5000000
#define BATCH    2000
#define N_PAIRS  1999000   // BATCH*(BATCH-1)/2

// Output offsets (float32 elements), concatenated in reference return order
#define OUT_BN      0
#define OUT_PAIRS0  2000
#define OUT_PAIRS1  2001000
#define OUT_ES0     4000000
#define OUT_ES1     9000000
#define OUT_T       14000000
#define OUT_S       19000000
#define OUT_M       24000000

// Workspace layout (bytes) — identical to R5/R6 (ws >= 40.25 MB proven)
#define WS_KEYS     0          // 10000 x u64 (dead after k_rank; fill1 aliases here)
#define WS_SEL      80000      // 10000 x i32
#define WS_BN       120000     // 2000  x i32
#define WS_CNT      128000     // 10000 x i32   (zeroed by memset)
#define WS_FILL     168000     // 10000 x i32   (init to off[] by k_scan_all)
#define WS_OFF      208000     // 10001 x i32
#define WS_SCRATCH  248064     // fast: 5M x u64 keys; fallback: 5M x u32 idx

// Sort key: (i<<38) | (j<<24) | (idx<<1) | state  (14+14+23+1 = 52 bits).
// Within a row i is constant, idx unique -> order == stable (j, idx).

#define RPB_LOG  7
#define NB1      79            // ceil(10000 / 128) coarse buckets
#define CHUNK    4096          // edges per partition block (256 thr x 16)

typedef unsigned long long u64;

// ---------------------------------------------------------------------------
__device__ __forceinline__ u64 score_key(int w, unsigned bits) {
  const float TINY = 1.17549435e-38f;
  float uf = __uint_as_float((bits >> 9) | 0x3f800000u) - 1.0f;
  float val = fmaxf(TINY, uf + TINY);
  float t1 = (float)log((double)val);            // inner log, rounded to f32
  float gmb = -(float)log((double)(-t1));        // outer log on f32-rounded input
  float score = (w > 0) ? ((float)log((double)w) + gmb) : (-INFINITY);
  unsigned fb = __float_as_uint(score);
  unsigned s = (fb & 0x80000000u) ? ~fb : (fb | 0x80000000u);
  unsigned d = ~s;
  return ((u64)d << 32) | (unsigned)w;
}

// JAX threefry2x32, partitionable mode: (x0,x1)=(0,i)+key; bits = out0^out1.
__global__ void k_scores(u64* __restrict__ keys) {
  int v = blockIdx.x * blockDim.x + threadIdx.x;
  if (v >= N_NODES) return;
  unsigned ks[3] = {0u, 19u, 0u ^ 19u ^ 0x1BD11BDAu};
  unsigned x0 = 0u + ks[0];
  unsigned x1 = (unsigned)v + ks[1];
  const int R0[4] = {13, 15, 26, 6};
  const int R1[4] = {17, 29, 16, 24};
#pragma unroll
  for (int g = 0; g < 5; ++g) {
    const int* R = (g & 1) ? R1 : R0;
#pragma unroll
    for (int r = 0; r < 4; ++r) {
      x0 += x1;
      x1 = (x1 << R[r]) | (x1 >> (32 - R[r]));
      x1 ^= x0;
    }
    x0 += ks[(g + 1) % 3];
    x1 += ks[(g + 2) % 3] + (unsigned)(g + 1);
  }
  keys[v] = score_key(v, x0 ^ x1);
}

// Rank each node's key among all 10000 (unique keys); selected iff rank < 2000.
__global__ void k_rank(const u64* __restrict__ keys, int* __restrict__ sel) {
  __shared__ u64 lk[2048];
  int v = blockIdx.x * blockDim.x + threadIdx.x;
  u64 kv = (v < N_NODES) ? keys[v] : 0xFFFFFFFFFFFFFFFFull;
  int cnt = 0;
  for (int base = 0; base < N_NODES; base += 2048) {
    int len = min(2048, N_NODES - base);
    for (int t = threadIdx.x; t < len; t += blockDim.x) lk[t] = keys[base + t];
    __syncthreads();
    for (int t = 0; t < len; ++t) cnt += (lk[t] < kv) ? 1 : 0;
    __syncthreads();
  }
  if (v < N_NODES) sel[v] = (cnt < BATCH) ? 1 : 0;
}

// Row histogram over source node i (LDS-local, merged with global atomics)
__global__ void k_hist(const int4* __restrict__ e_i4, int* __restrict__ cnt) {
  __shared__ int h[N_NODES];
  for (int t = threadIdx.x; t < N_NODES; t += blockDim.x) h[t] = 0;
  __syncthreads();
  int stride = gridDim.x * blockDim.x;
  for (int t = blockIdx.x * blockDim.x + threadIdx.x; t < N_EDGES / 4; t += stride) {
    int4 r = e_i4[t];
    atomicAdd(&h[r.x], 1);
    atomicAdd(&h[r.y], 1);
    atomicAdd(&h[r.z], 1);
    atomicAdd(&h[r.w], 1);
  }
  __syncthreads();
  for (int t = threadIdx.x; t < N_NODES; t += blockDim.x) {
    int c = h[t];
    if (c) atomicAdd(&cnt[t], c);
  }
}

// One block, 1024 threads. Phase 1: compaction scan sel -> batch_nodes.
// Phase 2: exclusive scan cnt -> off; fill[i] = off[i]; seed coarse-bucket
// cursors fill1[b] = off[b*128].
__global__ void k_scan_all(const int* __restrict__ sel, int* __restrict__ bn,
                           float* __restrict__ outbn, const int* __restrict__ cnt,
                           int* __restrict__ off, int* __restrict__ fill,
                           int* __restrict__ fill1) {
  __shared__ int ls[1024];
  const int PER = 10;  // 1024*10 >= 10000
  int tid = threadIdx.x;
  int base = tid * PER;
  {
    int s = 0;
    for (int k = 0; k < PER; ++k) {
      int i = base + k;
      if (i < N_NODES) s += sel[i];
    }
    ls[tid] = s;
    __syncthreads();
    for (int d = 1; d < 1024; d <<= 1) {
      int val = (tid >= d) ? ls[tid - d] : 0;
      __syncthreads();
      ls[tid] += val;
      __syncthreads();
    }
    int run = (tid > 0) ? ls[tid - 1] : 0;
    for (int k = 0; k < PER; ++k) {
      int i = base + k;
      if (i < N_NODES && sel[i]) {
        bn[run] = i;
        outbn[run] = (float)i;
        ++run;
      }
    }
  }
  __syncthreads();
  {
    int s = 0;
    for (int k = 0; k < PER; ++k) {
      int i = base + k;
      if (i < N_NODES) s += cnt[i];
    }
    ls[tid] = s;
    __syncthreads();
    for (int d = 1; d < 1024; d <<= 1) {
      int val = (tid >= d) ? ls[tid - d] : 0;
      __syncthreads();
      ls[tid] += val;
      __syncthreads();
    }
    int run = (tid > 0) ? ls[tid - 1] : 0;
    for (int k = 0; k < PER; ++k) {
      int i = base + k;
      if (i < N_NODES) {
        off[i] = run;
        fill[i] = run;
        if ((i & ((1 << RPB_LOG) - 1)) == 0) fill1[i >> RPB_LOG] = run;
        run += cnt[i];
      }
    }
    if (tid == 0) off[N_NODES] = N_EDGES;
  }
}

// batch_pairs via inverse triangular index. S(ii) = ii*(B-1) - ii*(ii-1)/2
__global__ void k_pairs(const int* __restrict__ bn, float* __restrict__ out) {
  int p = blockIdx.x * blockDim.x + threadIdx.x;
  if (p >= N_PAIRS) return;
  double t = 2.0 * BATCH - 1.0;
  int ii = (int)((t - sqrt(t * t - 8.0 * (double)p)) * 0.5);
  if (ii < 0) ii = 0;
  if (ii > BATCH - 2) ii = BATCH - 2;
  while (ii > 0 &&
         (long long)ii * (BATCH - 1) - (long long)ii * (ii - 1) / 2 > p) --ii;
  while ((long long)(ii + 1) * (BATCH - 1) - (long long)(ii + 1) * ii / 2 <= p) ++ii;
  long long S = (long long)ii * (BATCH - 1) - (long long)ii * (ii - 1) / 2;
  int jj = ii + 1 + (int)(p - S);
  out[p] = (float)bn[ii];
  out[N_PAIRS + p] = (float)bn[jj];
}

// P1: coarse partition into 79 buckets (i>>7) via LDS counting sort +
// sequential drain. Drain writes consecutive LDS positions -> consecutive
// global slots within each run => wave coalescer emits full-line stores.
__global__ void __launch_bounds__(256) k_part1(
    const int* __restrict__ e_i, const int* __restrict__ e_j,
    const int* __restrict__ st, int* __restrict__ fill1,
    u64* __restrict__ stage) {
  __shared__ u64 lkey[CHUNK];
  __shared__ int h[NB1], bstart[NB1], basec[NB1], cur[NB1];
  __shared__ int tcount_s;
  int tid = threadIdx.x;
  int c0 = blockIdx.x * CHUNK;
  int nloc = min(CHUNK, N_EDGES - c0);   // tail multiple of 4 (5e6 % 4096 = 2880)
  for (int t = tid; t < NB1; t += 256) h[t] = 0;
  __syncthreads();
  // Phase A: coalesced int4 read of e_i; hist; stash i in registers.
  int iv[CHUNK / 256];
  const int4* e_i4 = (const int4*)(e_i + c0);
#pragma unroll
  for (int k = 0; k < CHUNK / 1024; ++k) {
    int q = tid + 256 * k;          // int4 index within chunk
    int ebase = 4 * q;
    if (ebase < nloc) {
      int4 r = e_i4[q];
      iv[4 * k + 0] = r.x; iv[4 * k + 1] = r.y;
      iv[4 * k + 2] = r.z; iv[4 * k + 3] = r.w;
      atomicAdd(&h[r.x >> RPB_LOG], 1);
      atomicAdd(&h[r.y >> RPB_LOG], 1);
      atomicAdd(&h[r.z >> RPB_LOG], 1);
      atomicAdd(&h[r.w >> RPB_LOG], 1);
    } else {
      iv[4 * k + 0] = iv[4 * k + 1] = iv[4 * k + 2] = iv[4 * k + 3] = -1;
    }
  }
  __syncthreads();
  // Exclusive scan (79 entries, serial by thread 0 — trivial).
  if (tid == 0) {
    int run = 0;
    for (int b = 0; b < NB1; ++b) { bstart[b] = run; run += h[b]; }
    tcount_s = run;
  }
  __syncthreads();
  // Reserve global run ranges; init LDS cursors.
  for (int b = tid; b < NB1; b += 256) {
    basec[b] = h[b] ? atomicAdd(&fill1[b], h[b]) : 0;
    cur[b] = bstart[b];
  }
  __syncthreads();
  // Phase C: read e_j/st coalesced, build key, LDS scatter by bucket.
  const int4* e_j4 = (const int4*)(e_j + c0);
  const int4* st4 = (const int4*)(st + c0);
#pragma unroll
  for (int k = 0; k < CHUNK / 1024; ++k) {
    int q = tid + 256 * k;
    int ebase = 4 * q;
    if (ebase < nloc) {
      int4 jj = e_j4[q];
      int4 ss = st4[q];
      int js[4] = {jj.x, jj.y, jj.z, jj.w};
      int s4[4] = {ss.x, ss.y, ss.z, ss.w};
#pragma unroll
      for (int c = 0; c < 4; ++c) {
        int i = iv[4 * k + c];
        unsigned e = (unsigned)(c0 + ebase + c);
        int b = i >> RPB_LOG;
        int pos = atomicAdd(&cur[b], 1);
        lkey[pos] = ((u64)(unsigned)i << 38) | ((u64)(unsigned)js[c] << 24) |
                    ((u64)e << 1) | (u64)(unsigned)s4[c];
      }
    }
  }
  __syncthreads();
  // Drain: consecutive t -> consecutive dest within each bucket run.
  int tcount = tcount_s;
  for (int t = tid; t < tcount; t += 256) {
    u64 kv = lkey[t];
    int b = (int)(kv >> (38 + RPB_LOG));
    stage[basec[b] + (t - bstart[b])] = kv;
  }
}

// P2: fine partition bucket-grouped keys into exact row slots, same LDS
// counting-sort + coalesced-drain structure. Chunk spans <=2 coarse buckets
// => rows in [rowbase, rowbase+255].
__global__ void __launch_bounds__(256) k_part2(
    const u64* __restrict__ stage, int* __restrict__ fill,
    u64* __restrict__ sk) {
  __shared__ u64 lkey[CHUNK];
  __shared__ int h[256], bstart[256], baser[256], cur[256], ls[256];
  __shared__ int rowbase_s, tcount_s;
  int tid = threadIdx.x;
  int c0 = blockIdx.x * CHUNK;
  int nloc = min(CHUNK, N_EDGES - c0);
  h[tid] = 0;
  if (tid == 0)
    rowbase_s = ((int)(stage[c0] >> (38 + RPB_LOG))) << RPB_LOG;
  __syncthreads();
  int rowbase = rowbase_s;
  u64 kv[CHUNK / 256];
#pragma unroll
  for (int k = 0; k < CHUNK / 256; ++k) {
    int q = tid + 256 * k;
    if (q < nloc) {
      kv[k] = stage[c0 + q];
      atomicAdd(&h[(int)(kv[k] >> 38) - rowbase], 1);
    }
  }
  __syncthreads();
  // Exclusive scan of h[256] (Hillis-Steele, 8 rounds).
  ls[tid] = h[tid];
  __syncthreads();
  for (int d = 1; d < 256; d <<= 1) {
    int val = (tid >= d) ? ls[tid - d] : 0;
    __syncthreads();
    ls[tid] += val;
    __syncthreads();
  }
  bstart[tid] = ls[tid] - h[tid];            // exclusive
  if (tid == 255) tcount_s = ls[255];
  baser[tid] = h[tid] ? atomicAdd(&fill[rowbase + tid], h[tid]) : 0;
  cur[tid] = ls[tid] - h[tid];
  __syncthreads();
#pragma unroll
  for (int k = 0; k < CHUNK / 256; ++k) {
    int q = tid + 256 * k;
    if (q < nloc) {
      int lr = (int)(kv[k] >> 38) - rowbase;
      int pos = atomicAdd(&cur[lr], 1);
      lkey[pos] = kv[k];
    }
  }
  __syncthreads();
  int tcount = tcount_s;
  for (int t = tid; t < tcount; t += 256) {
    u64 v = lkey[t];
    int lr = (int)(v >> 38) - rowbase;
    sk[baser[lr] + (t - bstart[lr])] = v;
  }
}

// Rowsort: LDS bitonic with wave-local sub-passes. Thread t owns elements
// {t, t+256, ...}; wave w's elements form 64-aligned windows, so exchanges
// with j < 64 are entirely intra-wave (CDNA waves are lockstep; same-wave DS
// ops complete in order) -> no __syncthreads, just a compiler fence.
// Full barriers only when j >= 64 (cross-wave) or first local pass after one.
__device__ __forceinline__ void wave_fence() {
  asm volatile("" ::: "memory");          // no LDS caching across sub-passes
  __builtin_amdgcn_wave_barrier();        // no cross-sub-pass scheduling
}

__global__ void __launch_bounds__(256) k_rowsort_key(
    const u64* __restrict__ sk, const int* __restrict__ off,
    const float* __restrict__ times, const int* __restrict__ sel,
    float* __restrict__ out) {
  __shared__ u64 key[2048];
  int row = blockIdx.x;
  int o0 = off[row], o1 = off[row + 1];
  int len = o1 - o0;
  if (len <= 0) return;
  if (len > 2048) len = 2048;  // statistically impossible (>60 sigma)
  int M = 2;
  while (M < len) M <<= 1;
  // Load: thread t writes only its own elements -> own wave's windows.
  for (int t = threadIdx.x; t < M; t += blockDim.x)
    key[t] = (t < len) ? sk[o0 + t] : 0xFFFFFFFFFFFFFFFFull;
  wave_fence();
  int prev_cross = 0;
  for (int k = 2; k <= M; k <<= 1) {
    for (int j = k >> 1; j > 0; j >>= 1) {
      int cross = (j >= 64) ? 1 : 0;
      if (cross | prev_cross) __syncthreads();
      else wave_fence();
      for (int t = threadIdx.x; t < M; t += blockDim.x) {
        int ixj = t ^ j;
        if (ixj > t) {
          u64 a = key[t], b = key[ixj];
          bool up = ((t & k) == 0);
          if (up ? (a > b) : (a < b)) {
            key[t] = b;
            key[ixj] = a;
          }
        }
      }
      prev_cross = cross;
    }
  }
  if (prev_cross) __syncthreads();
  else wave_fence();
  int mi = sel[row];
  float frow = (float)row;
  for (int t = threadIdx.x; t < len; t += blockDim.x) {
    u64 k = key[t];
    int j = (int)((k >> 24) & 0x3FFFull);
    int idx = (int)((k >> 1) & 0x7FFFFFull);
    int st = (int)(k & 1ull);
    int p = o0 + t;
    out[OUT_ES0 + p] = frow;
    out[OUT_ES1 + p] = (float)j;
    bool m = (mi != 0) && (sel[j] != 0);
    float tm = 0.0f;
    if (m) tm = times[idx];                 // exec-masked gather, ~4% of edges
    out[OUT_T + p] = tm;
    out[OUT_S + p] = m ? (float)st : 0.0f;
    out[OUT_M + p] = m ? 1.0f : 0.0f;
  }
}

// ---- Fallback path (ws too small for u64 keys): R4-style 4B idx scatter ----
__global__ void __launch_bounds__(256) k_scatter_idx(
    const int4* __restrict__ e_i4, int* __restrict__ fill,
    unsigned* __restrict__ sk) {
  int t = blockIdx.x * blockDim.x + threadIdx.x;
  if (t >= N_EDGES / 4) return;
  int4 r = e_i4[t];
  unsigned e = 4u * (unsigned)t;
  int c0 = atomicAdd(&fill[r.x], 1);
  int c1 = atomicAdd(&fill[r.y], 1);
  int c2 = atomicAdd(&fill[r.z], 1);
  int c3 = atomicAdd(&fill[r.w], 1);
  sk[c0] = e;
  sk[c1] = e + 1;
  sk[c2] = e + 2;
  sk[c3] = e + 3;
}

__global__ void __launch_bounds__(256) k_rowsort_idx(
    const unsigned* __restrict__ sk, const int* __restrict__ e_j_arr,
    const int* __restrict__ off, const float* __restrict__ times,
    const int* __restrict__ states, const int* __restrict__ sel,
    float* __restrict__ out) {
  __shared__ u64 key[2048];
  int row = blockIdx.x;
  int o0 = off[row], o1 = off[row + 1];
  int len = o1 - o0;
  if (len <= 0) return;
  if (len > 2048) len = 2048;
  int M = 2;
  while (M < len) M <<= 1;
  for (int t = threadIdx.x; t < M; t += blockDim.x) {
    if (t < len) {
      unsigned e = sk[o0 + t];
      key[t] = ((u64)(unsigned)e_j_arr[e] << 32) | e;
    } else {
      key[t] = 0xFFFFFFFFFFFFFFFFull;
    }
  }
  __syncthreads();
  for (int k = 2; k <= M; k <<= 1) {
    for (int j = k >> 1; j > 0; j >>= 1) {
      for (int t = threadIdx.x; t < M; t += blockDim.x) {
        int ixj = t ^ j;
        if (ixj > t) {
          u64 a = key[t], b = key[ixj];
          bool up = ((t & k) == 0);
          if (up ? (a > b) : (a < b)) {
            key[t] = b;
            key[ixj] = a;
          }
        }
      }
      __syncthreads();
    }
  }
  int mi = sel[row];
  float frow = (float)row;
  for (int t = threadIdx.x; t < len; t += blockDim.x) {
    u64 k = key[t];
    int j = (int)(k >> 32);
    int idx = (int)(k & 0xFFFFFFFFull);
    int p = o0 + t;
    out[OUT_ES0 + p] = frow;
    out[OUT_ES1 + p] = (float)j;
    bool m = (mi != 0) && (sel[j] != 0);
    float tm = 0.0f, sv = 0.0f;
    if (m) {
      tm = times[idx];
      sv = (float)states[idx];
    }
    out[OUT_T + p] = tm;
    out[OUT_S + p] = sv;
    out[OUT_M + p] = m ? 1.0f : 0.0f;
  }
}

extern "C" void kernel_launch(void* const* d_in, const int* in_sizes, int n_in,
                              void* d_out, int out_size, void* d_ws, size_t ws_size,
                              hipStream_t stream) {
  const int* edges = (const int*)d_in[0];       // (2, E): [0..E)=i, [E..2E)=j
  const float* times = (const float*)d_in[1];
  const int* states = (const int*)d_in[2];
  const int* e_i = edges;
  const int* e_j = edges + N_EDGES;
  float* out = (float*)d_out;
  char* ws = (char*)d_ws;

  u64* keys = (u64*)(ws + WS_KEYS);
  int* fill1 = (int*)(ws + WS_KEYS);            // aliases keys (dead after k_rank)
  int* sel = (int*)(ws + WS_SEL);
  int* bn = (int*)(ws + WS_BN);
  int* cnt = (int*)(ws + WS_CNT);
  int* fill = (int*)(ws + WS_FILL);
  int* off = (int*)(ws + WS_OFF);
  u64* sk64 = (u64*)(ws + WS_SCRATCH);
  unsigned* sk32 = (unsigned*)(ws + WS_SCRATCH);
  // Staging buffer for P1 output: the es0/es1 output region (exactly 40 MB),
  // fully consumed by P2 before k_rowsort_key overwrites it.
  u64* stage = (u64*)(out + OUT_ES0);
  int use64 = (ws_size >= (size_t)WS_SCRATCH + 8ull * N_EDGES) ? 1 : 0;

  hipMemsetAsync(ws + WS_CNT, 0, 40000, stream);  // cnt only

  k_scores<<<(N_NODES + 255) / 256, 256, 0, stream>>>(keys);
  k_rank<<<(N_NODES + 255) / 256, 256, 0, stream>>>(keys, sel);
  k_hist<<<128, 256, 0, stream>>>((const int4*)e_i, cnt);
  k_scan_all<<<1, 1024, 0, stream>>>(sel, bn, out + OUT_BN, cnt, off, fill, fill1);
  k_pairs<<<(N_PAIRS + 255) / 256, 256, 0, stream>>>(bn, out + OUT_PAIRS0);
  if (use64) {
    int nblk = (N_EDGES + CHUNK - 1) / CHUNK;
    k_part1<<<nblk, 256, 0, stream>>>(e_i, e_j, states, fill1, stage);
    k_part2<<<nblk, 256, 0, stream>>>(stage, fill, sk64);
    k_rowsort_key<<<N_NODES, 256, 0, stream>>>(sk64, off, times, sel, out);
  } else {
    k_scatter_idx<<<(N_EDGES / 4 + 255) / 256, 256, 0, stream>>>(
        (const int4*)e_i, fill, sk32);
    k_rowsort_idx<<<N_NODES, 256, 0, stream>>>(sk32, e_j, off, times, states,
                                               sel, out);
  }
}

// Round 10
// 508.886 us; speedup vs baseline: 1.1524x; 1.1524x over previous
//
#include <hip/hip_runtime.h>
#include <stdint.h>
#include <math.h>

#define N_NODES  10000
#define N_EDGES  5000000
#define BATCH    2000
#define N_PAIRS  1999000   // BATCH*(BATCH-1)/2

// Output offsets (float32 elements), concatenated in reference return order
#define OUT_BN      0
#define OUT_PAIRS0  2000
#define OUT_PAIRS1  2001000
#define OUT_ES0     4000000
#define OUT_ES1     9000000
#define OUT_T       14000000
#define OUT_S       19000000
#define OUT_M       24000000

// Workspace layout (bytes) — identical to R5..R9 (ws >= 40.25 MB proven)
#define WS_KEYS     0          // 10000 x u64 (dead after k_rank; fill1 aliases here)
#define WS_SEL      80000      // 10000 x i32
#define WS_BN       120000     // 2000  x i32
#define WS_CNT      128000     // 10000 x i32   (zeroed by memset)
#define WS_FILL     168000     // 10000 x i32   (init to off[] by k_scan_all)
#define WS_OFF      208000     // 10001 x i32
#define WS_SCRATCH  248064     // fast: 5M x u64 keys; fallback: 5M x u32 idx

// Sort key: (i<<38) | (j<<24) | (idx<<1) | state  (14+14+23+1 = 52 bits).
// Within a row i is constant, idx unique -> order == stable (j, idx).

#define RPB_LOG  7
#define NB1      79            // ceil(10000 / 128) coarse buckets
#define CHUNK    4096          // edges per partition block (256 thr x 16)
#define NBIN     192           // row-sort j>>6 bins (max needed = 157)

typedef unsigned long long u64;

// ---------------------------------------------------------------------------
__device__ __forceinline__ u64 score_key(int w, unsigned bits) {
  const float TINY = 1.17549435e-38f;
  float uf = __uint_as_float((bits >> 9) | 0x3f800000u) - 1.0f;
  float val = fmaxf(TINY, uf + TINY);
  float t1 = (float)log((double)val);            // inner log, rounded to f32
  float gmb = -(float)log((double)(-t1));        // outer log on f32-rounded input
  float score = (w > 0) ? ((float)log((double)w) + gmb) : (-INFINITY);
  unsigned fb = __float_as_uint(score);
  unsigned s = (fb & 0x80000000u) ? ~fb : (fb | 0x80000000u);
  unsigned d = ~s;
  return ((u64)d << 32) | (unsigned)w;
}

// JAX threefry2x32, partitionable mode: (x0,x1)=(0,i)+key; bits = out0^out1.
__global__ void k_scores(u64* __restrict__ keys) {
  int v = blockIdx.x * blockDim.x + threadIdx.x;
  if (v >= N_NODES) return;
  unsigned ks[3] = {0u, 19u, 0u ^ 19u ^ 0x1BD11BDAu};
  unsigned x0 = 0u + ks[0];
  unsigned x1 = (unsigned)v + ks[1];
  const int R0[4] = {13, 15, 26, 6};
  const int R1[4] = {17, 29, 16, 24};
#pragma unroll
  for (int g = 0; g < 5; ++g) {
    const int* R = (g & 1) ? R1 : R0;
#pragma unroll
    for (int r = 0; r < 4; ++r) {
      x0 += x1;
      x1 = (x1 << R[r]) | (x1 >> (32 - R[r]));
      x1 ^= x0;
    }
    x0 += ks[(g + 1) % 3];
    x1 += ks[(g + 2) % 3] + (unsigned)(g + 1);
  }
  keys[v] = score_key(v, x0 ^ x1);
}

// Rank each node's key among all 10000 (unique keys); selected iff rank < 2000.
__global__ void k_rank(const u64* __restrict__ keys, int* __restrict__ sel) {
  __shared__ u64 lk[2048];
  int v = blockIdx.x * blockDim.x + threadIdx.x;
  u64 kv = (v < N_NODES) ? keys[v] : 0xFFFFFFFFFFFFFFFFull;
  int cnt = 0;
  for (int base = 0; base < N_NODES; base += 2048) {
    int len = min(2048, N_NODES - base);
    for (int t = threadIdx.x; t < len; t += blockDim.x) lk[t] = keys[base + t];
    __syncthreads();
    for (int t = 0; t < len; ++t) cnt += (lk[t] < kv) ? 1 : 0;
    __syncthreads();
  }
  if (v < N_NODES) sel[v] = (cnt < BATCH) ? 1 : 0;
}

// Row histogram over source node i (LDS-local, merged with global atomics)
__global__ void k_hist(const int4* __restrict__ e_i4, int* __restrict__ cnt) {
  __shared__ int h[N_NODES];
  for (int t = threadIdx.x; t < N_NODES; t += blockDim.x) h[t] = 0;
  __syncthreads();
  int stride = gridDim.x * blockDim.x;
  for (int t = blockIdx.x * blockDim.x + threadIdx.x; t < N_EDGES / 4; t += stride) {
    int4 r = e_i4[t];
    atomicAdd(&h[r.x], 1);
    atomicAdd(&h[r.y], 1);
    atomicAdd(&h[r.z], 1);
    atomicAdd(&h[r.w], 1);
  }
  __syncthreads();
  for (int t = threadIdx.x; t < N_NODES; t += blockDim.x) {
    int c = h[t];
    if (c) atomicAdd(&cnt[t], c);
  }
}

// One block, 1024 threads. Phase 1: compaction scan sel -> batch_nodes.
// Phase 2: exclusive scan cnt -> off; fill[i] = off[i]; seed coarse-bucket
// cursors fill1[b] = off[b*128].
__global__ void k_scan_all(const int* __restrict__ sel, int* __restrict__ bn,
                           float* __restrict__ outbn, const int* __restrict__ cnt,
                           int* __restrict__ off, int* __restrict__ fill,
                           int* __restrict__ fill1) {
  __shared__ int ls[1024];
  const int PER = 10;  // 1024*10 >= 10000
  int tid = threadIdx.x;
  int base = tid * PER;
  {
    int s = 0;
    for (int k = 0; k < PER; ++k) {
      int i = base + k;
      if (i < N_NODES) s += sel[i];
    }
    ls[tid] = s;
    __syncthreads();
    for (int d = 1; d < 1024; d <<= 1) {
      int val = (tid >= d) ? ls[tid - d] : 0;
      __syncthreads();
      ls[tid] += val;
      __syncthreads();
    }
    int run = (tid > 0) ? ls[tid - 1] : 0;
    for (int k = 0; k < PER; ++k) {
      int i = base + k;
      if (i < N_NODES && sel[i]) {
        bn[run] = i;
        outbn[run] = (float)i;
        ++run;
      }
    }
  }
  __syncthreads();
  {
    int s = 0;
    for (int k = 0; k < PER; ++k) {
      int i = base + k;
      if (i < N_NODES) s += cnt[i];
    }
    ls[tid] = s;
    __syncthreads();
    for (int d = 1; d < 1024; d <<= 1) {
      int val = (tid >= d) ? ls[tid - d] : 0;
      __syncthreads();
      ls[tid] += val;
      __syncthreads();
    }
    int run = (tid > 0) ? ls[tid - 1] : 0;
    for (int k = 0; k < PER; ++k) {
      int i = base + k;
      if (i < N_NODES) {
        off[i] = run;
        fill[i] = run;
        if ((i & ((1 << RPB_LOG) - 1)) == 0) fill1[i >> RPB_LOG] = run;
        run += cnt[i];
      }
    }
    if (tid == 0) off[N_NODES] = N_EDGES;
  }
}

// batch_pairs via inverse triangular index. S(ii) = ii*(B-1) - ii*(ii-1)/2
__global__ void k_pairs(const int* __restrict__ bn, float* __restrict__ out) {
  int p = blockIdx.x * blockDim.x + threadIdx.x;
  if (p >= N_PAIRS) return;
  double t = 2.0 * BATCH - 1.0;
  int ii = (int)((t - sqrt(t * t - 8.0 * (double)p)) * 0.5);
  if (ii < 0) ii = 0;
  if (ii > BATCH - 2) ii = BATCH - 2;
  while (ii > 0 &&
         (long long)ii * (BATCH - 1) - (long long)ii * (ii - 1) / 2 > p) --ii;
  while ((long long)(ii + 1) * (BATCH - 1) - (long long)(ii + 1) * ii / 2 <= p) ++ii;
  long long S = (long long)ii * (BATCH - 1) - (long long)ii * (ii - 1) / 2;
  int jj = ii + 1 + (int)(p - S);
  out[p] = (float)bn[ii];
  out[N_PAIRS + p] = (float)bn[jj];
}

// P1: coarse partition into 79 buckets (i>>7) via LDS counting sort +
// sequential drain. Drain writes consecutive LDS positions -> consecutive
// global slots within each run => wave coalescer emits full-line stores.
__global__ void __launch_bounds__(256) k_part1(
    const int* __restrict__ e_i, const int* __restrict__ e_j,
    const int* __restrict__ st, int* __restrict__ fill1,
    u64* __restrict__ stage) {
  __shared__ u64 lkey[CHUNK];
  __shared__ int h[NB1], bstart[NB1], basec[NB1], cur[NB1];
  __shared__ int tcount_s;
  int tid = threadIdx.x;
  int c0 = blockIdx.x * CHUNK;
  int nloc = min(CHUNK, N_EDGES - c0);   // tail multiple of 4 (5e6 % 4096 = 2880)
  for (int t = tid; t < NB1; t += 256) h[t] = 0;
  __syncthreads();
  // Phase A: coalesced int4 read of e_i; hist; stash i in registers.
  int iv[CHUNK / 256];
  const int4* e_i4 = (const int4*)(e_i + c0);
#pragma unroll
  for (int k = 0; k < CHUNK / 1024; ++k) {
    int q = tid + 256 * k;          // int4 index within chunk
    int ebase = 4 * q;
    if (ebase < nloc) {
      int4 r = e_i4[q];
      iv[4 * k + 0] = r.x; iv[4 * k + 1] = r.y;
      iv[4 * k + 2] = r.z; iv[4 * k + 3] = r.w;
      atomicAdd(&h[r.x >> RPB_LOG], 1);
      atomicAdd(&h[r.y >> RPB_LOG], 1);
      atomicAdd(&h[r.z >> RPB_LOG], 1);
      atomicAdd(&h[r.w >> RPB_LOG], 1);
    } else {
      iv[4 * k + 0] = iv[4 * k + 1] = iv[4 * k + 2] = iv[4 * k + 3] = -1;
    }
  }
  __syncthreads();
  // Exclusive scan (79 entries, serial by thread 0 — trivial).
  if (tid == 0) {
    int run = 0;
    for (int b = 0; b < NB1; ++b) { bstart[b] = run; run += h[b]; }
    tcount_s = run;
  }
  __syncthreads();
  // Reserve global run ranges; init LDS cursors.
  for (int b = tid; b < NB1; b += 256) {
    basec[b] = h[b] ? atomicAdd(&fill1[b], h[b]) : 0;
    cur[b] = bstart[b];
  }
  __syncthreads();
  // Phase C: read e_j/st coalesced, build key, LDS scatter by bucket.
  const int4* e_j4 = (const int4*)(e_j + c0);
  const int4* st4 = (const int4*)(st + c0);
#pragma unroll
  for (int k = 0; k < CHUNK / 1024; ++k) {
    int q = tid + 256 * k;
    int ebase = 4 * q;
    if (ebase < nloc) {
      int4 jj = e_j4[q];
      int4 ss = st4[q];
      int js[4] = {jj.x, jj.y, jj.z, jj.w};
      int s4[4] = {ss.x, ss.y, ss.z, ss.w};
#pragma unroll
      for (int c = 0; c < 4; ++c) {
        int i = iv[4 * k + c];
        unsigned e = (unsigned)(c0 + ebase + c);
        int b = i >> RPB_LOG;
        int pos = atomicAdd(&cur[b], 1);
        lkey[pos] = ((u64)(unsigned)i << 38) | ((u64)(unsigned)js[c] << 24) |
                    ((u64)e << 1) | (u64)(unsigned)s4[c];
      }
    }
  }
  __syncthreads();
  // Drain: consecutive t -> consecutive dest within each bucket run.
  int tcount = tcount_s;
  for (int t = tid; t < tcount; t += 256) {
    u64 kv = lkey[t];
    int b = (int)(kv >> (38 + RPB_LOG));
    stage[basec[b] + (t - bstart[b])] = kv;
  }
}

// P2: fine partition bucket-grouped keys into exact row slots, same LDS
// counting-sort + coalesced-drain structure. Chunk spans <=2 coarse buckets
// => rows in [rowbase, rowbase+255].
__global__ void __launch_bounds__(256) k_part2(
    const u64* __restrict__ stage, int* __restrict__ fill,
    u64* __restrict__ sk) {
  __shared__ u64 lkey[CHUNK];
  __shared__ int h[256], bstart[256], baser[256], cur[256], ls[256];
  __shared__ int rowbase_s, tcount_s;
  int tid = threadIdx.x;
  int c0 = blockIdx.x * CHUNK;
  int nloc = min(CHUNK, N_EDGES - c0);
  h[tid] = 0;
  if (tid == 0)
    rowbase_s = ((int)(stage[c0] >> (38 + RPB_LOG))) << RPB_LOG;
  __syncthreads();
  int rowbase = rowbase_s;
  u64 kv[CHUNK / 256];
#pragma unroll
  for (int k = 0; k < CHUNK / 256; ++k) {
    int q = tid + 256 * k;
    if (q < nloc) {
      kv[k] = stage[c0 + q];
      atomicAdd(&h[(int)(kv[k] >> 38) - rowbase], 1);
    }
  }
  __syncthreads();
  // Exclusive scan of h[256] (Hillis-Steele, 8 rounds).
  ls[tid] = h[tid];
  __syncthreads();
  for (int d = 1; d < 256; d <<= 1) {
    int val = (tid >= d) ? ls[tid - d] : 0;
    __syncthreads();
    ls[tid] += val;
    __syncthreads();
  }
  bstart[tid] = ls[tid] - h[tid];            // exclusive
  if (tid == 255) tcount_s = ls[255];
  baser[tid] = h[tid] ? atomicAdd(&fill[rowbase + tid], h[tid]) : 0;
  cur[tid] = ls[tid] - h[tid];
  __syncthreads();
#pragma unroll
  for (int k = 0; k < CHUNK / 256; ++k) {
    int q = tid + 256 * k;
    if (q < nloc) {
      int lr = (int)(kv[k] >> 38) - rowbase;
      int pos = atomicAdd(&cur[lr], 1);
      lkey[pos] = kv[k];
    }
  }
  __syncthreads();
  int tcount = tcount_s;
  for (int t = tid; t < tcount; t += 256) {
    u64 v = lkey[t];
    int lr = (int)(v >> 38) - rowbase;
    sk[baser[lr] + (t - bstart[lr])] = v;
  }
}

// Rowsort v3: bucket-partition + exact rank (replaces bitonic; LDS ops/elem
// ~14 vs ~90). Phase A: bucket by j>>6 (<=157 bins), LDS hist + wave-0
// shuffle scan + atomic scatter into buf2 (unstable within bucket, fine).
// Phase B: each element scans its own bucket counting keys < own (keys
// unique -> ranks unique), writes buf3[start+rank], strided coalesced emit.
__global__ void __launch_bounds__(256) k_rowsort_key(
    const u64* __restrict__ sk, const int* __restrict__ off,
    const float* __restrict__ times, const int* __restrict__ sel,
    float* __restrict__ out) {
  __shared__ u64 buf2[1024];
  __shared__ u64 buf3[1024];
  __shared__ int hist[NBIN], bstart[NBIN], cur[NBIN];
  int tid = threadIdx.x;
  int row = blockIdx.x;
  int o0 = off[row], o1 = off[row + 1];
  int len = o1 - o0;
  if (len <= 0) return;
  if (len > 1024) len = 1024;  // >23 sigma, statistically impossible
  int jb = (row + 1) >> 6;     // min possible j>>6 for this row
  for (int t = tid; t < NBIN; t += 256) hist[t] = 0;
  __syncthreads();
  // Load (strided, coalesced) into regs; histogram bins.
  u64 kv[4];
  int dv[4];
#pragma unroll
  for (int k = 0; k < 4; ++k) {
    int t = tid + 256 * k;
    if (t < len) {
      u64 v = sk[o0 + t];
      kv[k] = v;
      int d = (int)((v >> 30) & 0xFF) - jb;   // (j>>6) - jb
      dv[k] = d;
      atomicAdd(&hist[d], 1);
    } else {
      dv[k] = -1;
    }
  }
  __syncthreads();
  // Exclusive scan of NBIN bins by wave 0 (3 bins/lane + shuffle scan).
  if (tid < 64) {
    int b0 = tid * 3;
    int c0 = hist[b0], c1 = hist[b0 + 1], c2 = hist[b0 + 2];
    int sum = c0 + c1 + c2;
    int inc = sum;
#pragma unroll
    for (int d = 1; d < 64; d <<= 1) {
      int v = __shfl_up(inc, d, 64);
      if (tid >= d) inc += v;
    }
    int excl = inc - sum;
    bstart[b0] = excl;
    bstart[b0 + 1] = excl + c0;
    bstart[b0 + 2] = excl + c0 + c1;
    cur[b0] = excl;
    cur[b0 + 1] = excl + c0;
    cur[b0 + 2] = excl + c0 + c1;
  }
  __syncthreads();
  // Scatter into buckets (order within bucket arbitrary).
#pragma unroll
  for (int k = 0; k < 4; ++k) {
    if (dv[k] >= 0) {
      int pos = atomicAdd(&cur[dv[k]], 1);
      buf2[pos] = kv[k];
    }
  }
  __syncthreads();
  // Rank within bucket by full key; place into final slot.
#pragma unroll
  for (int k = 0; k < 4; ++k) {
    if (dv[k] >= 0) {
      u64 me = kv[k];
      int s0 = bstart[dv[k]];
      int s1 = s0 + hist[dv[k]];
      int r = 0;
      for (int q = s0; q < s1; ++q) r += (buf2[q] < me) ? 1 : 0;
      buf3[s0 + r] = me;
    }
  }
  __syncthreads();
  // Coalesced emit.
  int mi = sel[row];
  float frow = (float)row;
  for (int t = tid; t < len; t += 256) {
    u64 k = buf3[t];
    int j = (int)((k >> 24) & 0x3FFFull);
    int idx = (int)((k >> 1) & 0x7FFFFFull);
    int st = (int)(k & 1ull);
    int p = o0 + t;
    out[OUT_ES0 + p] = frow;
    out[OUT_ES1 + p] = (float)j;
    bool m = (mi != 0) && (sel[j] != 0);
    float tm = 0.0f;
    if (m) tm = times[idx];                 // exec-masked gather, ~4% of edges
    out[OUT_T + p] = tm;
    out[OUT_S + p] = m ? (float)st : 0.0f;
    out[OUT_M + p] = m ? 1.0f : 0.0f;
  }
}

// ---- Fallback path (ws too small for u64 keys): R4-style 4B idx scatter ----
__global__ void __launch_bounds__(256) k_scatter_idx(
    const int4* __restrict__ e_i4, int* __restrict__ fill,
    unsigned* __restrict__ sk) {
  int t = blockIdx.x * blockDim.x + threadIdx.x;
  if (t >= N_EDGES / 4) return;
  int4 r = e_i4[t];
  unsigned e = 4u * (unsigned)t;
  int c0 = atomicAdd(&fill[r.x], 1);
  int c1 = atomicAdd(&fill[r.y], 1);
  int c2 = atomicAdd(&fill[r.z], 1);
  int c3 = atomicAdd(&fill[r.w], 1);
  sk[c0] = e;
  sk[c1] = e + 1;
  sk[c2] = e + 2;
  sk[c3] = e + 3;
}

__global__ void __launch_bounds__(256) k_rowsort_idx(
    const unsigned* __restrict__ sk, const int* __restrict__ e_j_arr,
    const int* __restrict__ off, const float* __restrict__ times,
    const int* __restrict__ states, const int* __restrict__ sel,
    float* __restrict__ out) {
  __shared__ u64 key[2048];
  int row = blockIdx.x;
  int o0 = off[row], o1 = off[row + 1];
  int len = o1 - o0;
  if (len <= 0) return;
  if (len > 2048) len = 2048;
  int M = 2;
  while (M < len) M <<= 1;
  for (int t = threadIdx.x; t < M; t += blockDim.x) {
    if (t < len) {
      unsigned e = sk[o0 + t];
      key[t] = ((u64)(unsigned)e_j_arr[e] << 32) | e;
    } else {
      key[t] = 0xFFFFFFFFFFFFFFFFull;
    }
  }
  __syncthreads();
  for (int k = 2; k <= M; k <<= 1) {
    for (int j = k >> 1; j > 0; j >>= 1) {
      for (int t = threadIdx.x; t < M; t += blockDim.x) {
        int ixj = t ^ j;
        if (ixj > t) {
          u64 a = key[t], b = key[ixj];
          bool up = ((t & k) == 0);
          if (up ? (a > b) : (a < b)) {
            key[t] = b;
            key[ixj] = a;
          }
        }
      }
      __syncthreads();
    }
  }
  int mi = sel[row];
  float frow = (float)row;
  for (int t = threadIdx.x; t < len; t += blockDim.x) {
    u64 k = key[t];
    int j = (int)(k >> 32);
    int idx = (int)(k & 0xFFFFFFFFull);
    int p = o0 + t;
    out[OUT_ES0 + p] = frow;
    out[OUT_ES1 + p] = (float)j;
    bool m = (mi != 0) && (sel[j] != 0);
    float tm = 0.0f, sv = 0.0f;
    if (m) {
      tm = times[idx];
      sv = (float)states[idx];
    }
    out[OUT_T + p] = tm;
    out[OUT_S + p] = sv;
    out[OUT_M + p] = m ? 1.0f : 0.0f;
  }
}

extern "C" void kernel_launch(void* const* d_in, const int* in_sizes, int n_in,
                              void* d_out, int out_size, void* d_ws, size_t ws_size,
                              hipStream_t stream) {
  const int* edges = (const int*)d_in[0];       // (2, E): [0..E)=i, [E..2E)=j
  const float* times = (const float*)d_in[1];
  const int* states = (const int*)d_in[2];
  const int* e_i = edges;
  const int* e_j = edges + N_EDGES;
  float* out = (float*)d_out;
  char* ws = (char*)d_ws;

  u64* keys = (u64*)(ws + WS_KEYS);
  int* fill1 = (int*)(ws + WS_KEYS);            // aliases keys (dead after k_rank)
  int* sel = (int*)(ws + WS_SEL);
  int* bn = (int*)(ws + WS_BN);
  int* cnt = (int*)(ws + WS_CNT);
  int* fill = (int*)(ws + WS_FILL);
  int* off = (int*)(ws + WS_OFF);
  u64* sk64 = (u64*)(ws + WS_SCRATCH);
  unsigned* sk32 = (unsigned*)(ws + WS_SCRATCH);
  // Staging buffer for P1 output: the es0/es1 output region (exactly 40 MB),
  // fully consumed by P2 before k_rowsort_key overwrites it.
  u64* stage = (u64*)(out + OUT_ES0);
  int use64 = (ws_size >= (size_t)WS_SCRATCH + 8ull * N_EDGES) ? 1 : 0;

  hipMemsetAsync(ws + WS_CNT, 0, 40000, stream);  // cnt only

  k_scores<<<(N_NODES + 255) / 256, 256, 0, stream>>>(keys);
  k_rank<<<(N_NODES + 255) / 256, 256, 0, stream>>>(keys, sel);
  k_hist<<<128, 256, 0, stream>>>((const int4*)e_i, cnt);
  k_scan_all<<<1, 1024, 0, stream>>>(sel, bn, out + OUT_BN, cnt, off, fill, fill1);
  k_pairs<<<(N_PAIRS + 255) / 256, 256, 0, stream>>>(bn, out + OUT_PAIRS0);
  if (use64) {
    int nblk = (N_EDGES + CHUNK - 1) / CHUNK;
    k_part1<<<nblk, 256, 0, stream>>>(e_i, e_j, states, fill1, stage);
    k_part2<<<nblk, 256, 0, stream>>>(stage, fill, sk64);
    k_rowsort_key<<<N_NODES, 256, 0, stream>>>(sk64, off, times, sel, out);
  } else {
    k_scatter_idx<<<(N_EDGES / 4 + 255) / 256, 256, 0, stream>>>(
        (const int4*)e_i, fill, sk32);
    k_rowsort_idx<<<N_NODES, 256, 0, stream>>>(sk32, e_j, off, times, states,
                                               sel, out);
  }
}